// Round 2
// baseline (575.932 us; speedup 1.0000x reference)
//
#include <hip/hip_runtime.h>
#include <hip/hip_bf16.h>
#include <stdint.h>

// ---------------------------------------------------------------------------
// E8RHT MLP:  out = ( gelu( rht(x) @ Wup^T ) -> rht -> @ Wdn^T )
// Folded: W_eff[o,:] = signs * blockwise-FWHT(wq[o,:]) * scale[o] / sqrt(128),
// so the hot path is two plain B^T GEMMs with a fused gelu epilogue.
// Robustness: runtime input-dtype detection (f32 vs bf16) + ws-adaptive
// T-slicing so the activation buffer fits whatever ws_size we get.
// ---------------------------------------------------------------------------

typedef __attribute__((ext_vector_type(8))) short short8;
typedef __attribute__((ext_vector_type(4))) float floatx4;

__device__ __forceinline__ float bf2f(unsigned int u16) {
    union { unsigned int i; float f; } v;
    v.i = u16 << 16;
    return v.f;
}

__device__ __forceinline__ unsigned short f2bf(float f) {
    union { float f; unsigned int i; } v;
    v.f = f;
    unsigned int r = v.i + 0x7FFFu + ((v.i >> 16) & 1u);  // RTNE
    return (unsigned short)(r >> 16);
}

// tanh-approx gelu, matching jax.nn.gelu(approximate=True).
// tanh(u) = 1 - 2/(exp(2u)+1): overflow-safe (exp->inf => tanh->1).
__device__ __forceinline__ float gelu_tanh(float x) {
    float u = 0.7978845608028654f * (x + 0.044715f * x * x * x);
    float e = __expf(2.0f * u);
    float t = 1.0f - 2.0f / (e + 1.0f);
    return 0.5f * x * (1.0f + t);
}

// ---------------------------------------------------------------------------
// Input dtype detection. signs[0] is exactly +-1:
//   f32:  0x3F800000 / 0xBF800000  -> low 16 bits == 0
//   bf16: first ushort = 0x3F80 / 0xBF80 -> low 16 bits != 0
// flag = 1 for bf16 inputs, 0 for f32 inputs.
// ---------------------------------------------------------------------------
__global__ void detect_dtype(const unsigned int* __restrict__ signs_raw,
                             int* __restrict__ flag) {
    *flag = ((*signs_raw) & 0xFFFFu) ? 1 : 0;
}

// ---------------------------------------------------------------------------
// Normalize x to bf16 in ws (copy if already bf16, convert if f32).
// One thread per 8 elements.
// ---------------------------------------------------------------------------
__global__ void convert_x(const void* __restrict__ xin,
                          unsigned short* __restrict__ xout,
                          const int* __restrict__ flag, int total8) {
    int t = blockIdx.x * blockDim.x + threadIdx.x;
    if (t >= total8) return;
    size_t e = (size_t)t * 8;
    if (flag[0]) {
        *(uint4*)(xout + e) = *(const uint4*)((const unsigned short*)xin + e);
    } else {
        const float* xf = (const float*)xin + e;
        uint4 r;
        r.x = (unsigned)f2bf(xf[0]) | ((unsigned)f2bf(xf[1]) << 16);
        r.y = (unsigned)f2bf(xf[2]) | ((unsigned)f2bf(xf[3]) << 16);
        r.z = (unsigned)f2bf(xf[4]) | ((unsigned)f2bf(xf[5]) << 16);
        r.w = (unsigned)f2bf(xf[6]) | ((unsigned)f2bf(xf[7]) << 16);
        *(uint4*)(xout + e) = r;
    }
}

// ---------------------------------------------------------------------------
// Weight transform: W_eff[o, blk*128+b] =
//   signs[blk*128+b] * scale[o] * (1/sqrt(128)) * FWHT_128(wq[o, blk*128+:])[b]
// One wave per (o, blk). Lane holds elements 2l, 2l+1; FWHT = in-lane pair
// butterfly + 6 shfl_xor lane stages. Output always bf16.
// ---------------------------------------------------------------------------
__global__ void fwht_weights(const void* __restrict__ wq,
                             const void* __restrict__ scale,
                             const void* __restrict__ signs,
                             unsigned short* __restrict__ out,
                             const int* __restrict__ flag,
                             int D, int nblk, int total_waves) {
    int gwave = (int)((blockIdx.x * blockDim.x + threadIdx.x) >> 6);
    int lane = threadIdx.x & 63;
    if (gwave >= total_waves) return;
    int o = gwave / nblk;
    int blk = gwave - o * nblk;
    size_t base = (size_t)o * D + (size_t)blk * 128;

    float v0, v1, s0, s1, sc;
    if (flag[0]) {  // bf16 inputs
        unsigned int p = ((const unsigned int*)((const unsigned short*)wq + base))[lane];
        v0 = bf2f(p & 0xffffu);
        v1 = bf2f(p >> 16);
        unsigned int sp =
            ((const unsigned int*)((const unsigned short*)signs + (size_t)blk * 128))[lane];
        s0 = bf2f(sp & 0xffffu);
        s1 = bf2f(sp >> 16);
        sc = bf2f(((const unsigned short*)scale)[o]);
    } else {  // f32 inputs
        const float* wf = (const float*)wq + base;
        v0 = wf[2 * lane];
        v1 = wf[2 * lane + 1];
        const float* sf = (const float*)signs + (size_t)blk * 128;
        s0 = sf[2 * lane];
        s1 = sf[2 * lane + 1];
        sc = ((const float*)scale)[o];
    }

    // stage len=1 (positions 2l, 2l+1 in-lane)
    {
        float a = v0, b = v1;
        v0 = a + b;
        v1 = a - b;
    }
    // stages len=2..64 -> lane-bit butterflies
#pragma unroll
    for (int m = 1; m <= 32; m <<= 1) {
        float p0 = __shfl_xor(v0, m, 64);
        float p1 = __shfl_xor(v1, m, 64);
        if (lane & m) {
            v0 = p0 - v0;
            v1 = p1 - v1;
        } else {
            v0 = v0 + p0;
            v1 = v1 + p1;
        }
    }

    sc *= 0.08838834764831845f;  // 1/sqrt(128)
    unsigned short o0 = f2bf(v0 * sc * s0);
    unsigned short o1 = f2bf(v1 * sc * s1);
    ((unsigned int*)(out + base))[lane] = (unsigned int)o0 | ((unsigned int)o1 << 16);
}

// ---------------------------------------------------------------------------
// B^T GEMM: C[M,N] = A[M,K] @ B[N,K]^T, bf16 in, fp32 accum.
// 128x128 tile, BK=32, 256 threads (4 waves, 2x2), 4x4 of 16x16x32 MFMA/wave,
// global_load_lds width=16 staging (m97 structure).
// ACT=1 fuses tanh-gelu. OUT_DYN=1: store f32 or bf16 per flag (d_out);
// OUT_DYN=0: always bf16 (internal activation buffer).
// rowOff: global C row offset for T-sliced operation.
// ---------------------------------------------------------------------------
template <int ACT, int OUT_DYN>
__global__ __launch_bounds__(256) void gemm_bt(const unsigned short* __restrict__ A,
                                               const unsigned short* __restrict__ B,
                                               void* __restrict__ C,
                                               const int* __restrict__ flag,
                                               int N, int K, int rowOff) {
    __shared__ unsigned short As[128 * 32];
    __shared__ unsigned short Bs[128 * 32];

    const int tid = threadIdx.x;
    const int lane = tid & 63;
    const int wave = tid >> 6;
    const int tileM = blockIdx.y * 128;
    const int tileN = blockIdx.x * 128;
    const int fl = OUT_DYN ? flag[0] : 1;

    const int wm = wave & 1, wn = wave >> 1;
    const int m0 = wm * 64, n0 = wn * 64;

    // staging: wave w fills LDS bytes [w*2048, w*2048+2048) = rows w*32..w*32+31.
    // lane L loads 16B at row w*32 + L/4 (+16 for chunk 1), col (L&3)*8.
    const int srow = wave * 32 + (lane >> 2);
    const int scol = (lane & 3) * 8;

    floatx4 acc[4][4];
#pragma unroll
    for (int i = 0; i < 4; i++)
#pragma unroll
        for (int j = 0; j < 4; j++) acc[i][j] = (floatx4)0.0f;

    const int fr = lane & 15;        // fragment row within 16
    const int fk = (lane >> 4) * 8;  // fragment k offset

    const unsigned short* Abase = A + (size_t)(tileM + srow) * K + scol;
    const unsigned short* Bbase = B + (size_t)(tileN + srow) * K + scol;
    unsigned short* AsDst = As + wave * 1024;  // elements; chunk 1 at +512
    unsigned short* BsDst = Bs + wave * 1024;

    for (int k0 = 0; k0 < K; k0 += 32) {
        __builtin_amdgcn_global_load_lds(
            (const __attribute__((address_space(1))) unsigned int*)(Abase + k0),
            (__attribute__((address_space(3))) unsigned int*)(AsDst), 16, 0, 0);
        __builtin_amdgcn_global_load_lds(
            (const __attribute__((address_space(1))) unsigned int*)(Abase + k0 + (size_t)16 * K),
            (__attribute__((address_space(3))) unsigned int*)(AsDst + 512), 16, 0, 0);
        __builtin_amdgcn_global_load_lds(
            (const __attribute__((address_space(1))) unsigned int*)(Bbase + k0),
            (__attribute__((address_space(3))) unsigned int*)(BsDst), 16, 0, 0);
        __builtin_amdgcn_global_load_lds(
            (const __attribute__((address_space(1))) unsigned int*)(Bbase + k0 + (size_t)16 * K),
            (__attribute__((address_space(3))) unsigned int*)(BsDst + 512), 16, 0, 0);

        __syncthreads();

        short8 af[4], bfr[4];
#pragma unroll
        for (int i = 0; i < 4; i++) {
            af[i] = *(const short8*)&As[(m0 + i * 16 + fr) * 32 + fk];
            bfr[i] = *(const short8*)&Bs[(n0 + i * 16 + fr) * 32 + fk];
        }
#pragma unroll
        for (int mi = 0; mi < 4; mi++)
#pragma unroll
            for (int ni = 0; ni < 4; ni++)
                acc[mi][ni] = __builtin_amdgcn_mfma_f32_16x16x32_bf16(af[mi], bfr[ni],
                                                                      acc[mi][ni], 0, 0, 0);
        __syncthreads();
    }

    // epilogue: C/D layout col=lane&15, row=(lane>>4)*4+reg
#pragma unroll
    for (int mi = 0; mi < 4; mi++) {
        int rbase = tileM + m0 + mi * 16 + (lane >> 4) * 4;
#pragma unroll
        for (int ni = 0; ni < 4; ni++) {
            int c = tileN + n0 + ni * 16 + (lane & 15);
#pragma unroll
            for (int r = 0; r < 4; r++) {
                float v = acc[mi][ni][r];
                if (ACT) v = gelu_tanh(v);
                size_t idx = (size_t)(rowOff + rbase + r) * N + c;
                if (fl)
                    ((unsigned short*)C)[idx] = f2bf(v);
                else
                    ((float*)C)[idx] = v;
            }
        }
    }
}

// ---------------------------------------------------------------------------
extern "C" void kernel_launch(void* const* d_in, const int* in_sizes, int n_in,
                              void* d_out, int out_size, void* d_ws, size_t ws_size,
                              hipStream_t stream) {
    const int T = 16384, D_IN = 1024, D_MID = 4096, D_OUT = 1024;

    // ws layout: [flag 256B][w_up 8MiB][w_dn 8MiB][x_bf16 32MiB][a slice ...]
    char* ws = (char*)d_ws;
    int* flag = (int*)ws;
    unsigned short* w_up = (unsigned short*)(ws + 256);
    unsigned short* w_dn = w_up + (size_t)D_MID * D_IN;
    unsigned short* x_bf = w_dn + (size_t)D_OUT * D_MID;
    unsigned short* a_buf = x_bf + (size_t)T * D_IN;

    size_t used = 256 + ((size_t)D_MID * D_IN + (size_t)D_OUT * D_MID + (size_t)T * D_IN) * 2;
    size_t avail = ws_size > used ? ws_size - used : 0;
    long tc = (long)(avail / ((size_t)D_MID * 2));
    tc = (tc / 128) * 128;
    if (tc > T) tc = T;
    if (tc < 128) tc = 128;  // last resort; needs ws_size >= ~49 MiB
    const int Tc = (int)tc;

    detect_dtype<<<dim3(1), dim3(1), 0, stream>>>((const unsigned int*)d_in[5], flag);

    {
        int total8 = T * D_IN / 8;
        convert_x<<<dim3((total8 + 255) / 256), dim3(256), 0, stream>>>(d_in[0], x_bf, flag,
                                                                        total8);
    }
    {
        int waves = D_MID * (D_IN / 128);  // 32768
        fwht_weights<<<dim3(waves / 4), dim3(256), 0, stream>>>(d_in[1], d_in[2], d_in[5], w_up,
                                                                flag, D_IN, D_IN / 128, waves);
    }
    {
        int waves = D_OUT * (D_MID / 128);  // 32768
        fwht_weights<<<dim3(waves / 4), dim3(256), 0, stream>>>(d_in[3], d_in[4], d_in[6], w_dn,
                                                                flag, D_MID, D_MID / 128, waves);
    }

    for (int r0 = 0; r0 < T; r0 += Tc) {
        int Ms = (T - r0 < Tc) ? (T - r0) : Tc;
        // a = gelu(x_slice @ w_up^T)   [Ms, D_MID] bf16
        gemm_bt<1, 0><<<dim3(D_MID / 128, Ms / 128), dim3(256), 0, stream>>>(
            x_bf + (size_t)r0 * D_IN, w_up, a_buf, flag, D_MID, D_IN, 0);
        // out_slice = a @ w_dn^T       [Ms, D_OUT] f32 or bf16 per flag
        gemm_bt<0, 1><<<dim3(D_OUT / 128, Ms / 128), dim3(256), 0, stream>>>(
            a_buf, w_dn, d_out, flag, D_OUT, D_MID, r0);
    }
}

// Round 3
// 554.714 us; speedup vs baseline: 1.0383x; 1.0383x over previous
//
#include <hip/hip_runtime.h>
#include <hip/hip_bf16.h>
#include <stdint.h>

// ---------------------------------------------------------------------------
// E8RHT MLP:  out = ( gelu( rht(x) @ Wup^T ) -> rht -> @ Wdn^T )
// Folded: W_eff[o,:] = signs * blockwise-FWHT(wq[o,:]) * scale[o] / sqrt(128),
// so the hot path is two plain B^T GEMMs with a fused gelu epilogue.
// R3: XCD-aware L2-locality swizzle (each XCD owns an M-strip; GM-panel sweep)
// to kill the 14x L2-miss over-fetch seen in R2 (FETCH 575MB vs 40MB ideal).
// ---------------------------------------------------------------------------

typedef __attribute__((ext_vector_type(8))) short short8;
typedef __attribute__((ext_vector_type(4))) float floatx4;

__device__ __forceinline__ float bf2f(unsigned int u16) {
    union { unsigned int i; float f; } v;
    v.i = u16 << 16;
    return v.f;
}

__device__ __forceinline__ unsigned short f2bf(float f) {
    union { float f; unsigned int i; } v;
    v.f = f;
    unsigned int r = v.i + 0x7FFFu + ((v.i >> 16) & 1u);  // RTNE
    return (unsigned short)(r >> 16);
}

// tanh-approx gelu, matching jax.nn.gelu(approximate=True).
__device__ __forceinline__ float gelu_tanh(float x) {
    float u = 0.7978845608028654f * (x + 0.044715f * x * x * x);
    float e = __expf(2.0f * u);
    float t = 1.0f - 2.0f / (e + 1.0f);
    return 0.5f * x * (1.0f + t);
}

// ---------------------------------------------------------------------------
// Input dtype detection: signs[0] is exactly +-1. f32 -> low 16 bits of the
// first word are 0; bf16 -> first ushort is 0x3F80/0xBF80 != 0.
// ---------------------------------------------------------------------------
__global__ void detect_dtype(const unsigned int* __restrict__ signs_raw,
                             int* __restrict__ flag) {
    *flag = ((*signs_raw) & 0xFFFFu) ? 1 : 0;
}

// ---------------------------------------------------------------------------
// Normalize x to bf16 in ws. One thread per 8 elements.
// ---------------------------------------------------------------------------
__global__ void convert_x(const void* __restrict__ xin,
                          unsigned short* __restrict__ xout,
                          const int* __restrict__ flag, int total8) {
    int t = blockIdx.x * blockDim.x + threadIdx.x;
    if (t >= total8) return;
    size_t e = (size_t)t * 8;
    if (flag[0]) {
        *(uint4*)(xout + e) = *(const uint4*)((const unsigned short*)xin + e);
    } else {
        const float* xf = (const float*)xin + e;
        uint4 r;
        r.x = (unsigned)f2bf(xf[0]) | ((unsigned)f2bf(xf[1]) << 16);
        r.y = (unsigned)f2bf(xf[2]) | ((unsigned)f2bf(xf[3]) << 16);
        r.z = (unsigned)f2bf(xf[4]) | ((unsigned)f2bf(xf[5]) << 16);
        r.w = (unsigned)f2bf(xf[6]) | ((unsigned)f2bf(xf[7]) << 16);
        *(uint4*)(xout + e) = r;
    }
}

// ---------------------------------------------------------------------------
// Weight transform: W_eff[o, blk*128+b] =
//   signs[blk*128+b] * scale[o] * (1/sqrt(128)) * FWHT_128(wq[o, blk*128+:])[b]
// One wave per (o, blk); in-lane pair butterfly + 6 shfl_xor stages.
// ---------------------------------------------------------------------------
__global__ void fwht_weights(const void* __restrict__ wq,
                             const void* __restrict__ scale,
                             const void* __restrict__ signs,
                             unsigned short* __restrict__ out,
                             const int* __restrict__ flag,
                             int D, int nblk, int total_waves) {
    int gwave = (int)((blockIdx.x * blockDim.x + threadIdx.x) >> 6);
    int lane = threadIdx.x & 63;
    if (gwave >= total_waves) return;
    int o = gwave / nblk;
    int blk = gwave - o * nblk;
    size_t base = (size_t)o * D + (size_t)blk * 128;

    float v0, v1, s0, s1, sc;
    if (flag[0]) {  // bf16 inputs
        unsigned int p = ((const unsigned int*)((const unsigned short*)wq + base))[lane];
        v0 = bf2f(p & 0xffffu);
        v1 = bf2f(p >> 16);
        unsigned int sp =
            ((const unsigned int*)((const unsigned short*)signs + (size_t)blk * 128))[lane];
        s0 = bf2f(sp & 0xffffu);
        s1 = bf2f(sp >> 16);
        sc = bf2f(((const unsigned short*)scale)[o]);
    } else {  // f32 inputs
        const float* wf = (const float*)wq + base;
        v0 = wf[2 * lane];
        v1 = wf[2 * lane + 1];
        const float* sf = (const float*)signs + (size_t)blk * 128;
        s0 = sf[2 * lane];
        s1 = sf[2 * lane + 1];
        sc = ((const float*)scale)[o];
    }

    {
        float a = v0, b = v1;
        v0 = a + b;
        v1 = a - b;
    }
#pragma unroll
    for (int m = 1; m <= 32; m <<= 1) {
        float p0 = __shfl_xor(v0, m, 64);
        float p1 = __shfl_xor(v1, m, 64);
        if (lane & m) {
            v0 = p0 - v0;
            v1 = p1 - v1;
        } else {
            v0 = v0 + p0;
            v1 = v1 + p1;
        }
    }

    sc *= 0.08838834764831845f;  // 1/sqrt(128)
    unsigned short o0 = f2bf(v0 * sc * s0);
    unsigned short o1 = f2bf(v1 * sc * s1);
    ((unsigned int*)(out + base))[lane] = (unsigned int)o0 | ((unsigned int)o1 << 16);
}

// ---------------------------------------------------------------------------
// B^T GEMM: C[M,N] = A[M,K] @ B[N,K]^T, bf16 in, fp32 accum.
// 128x128 tile, BK=32, 4 waves (2x2), 4x4 of 16x16x32 MFMA/wave, m97 staging.
// 1D grid + XCD-aware swizzle:
//   strip>0: XCD j = flat%8 owns m-tiles [j*strip, (j+1)*strip); within the
//            strip, panels of GM m-tiles swept n-outer / m-inner so the live
//            L2 working set is GM A-tiles + 1 B-tile.
//   strip==0: plain GM-panel mapping (fallback when MT%8 != 0).
// ---------------------------------------------------------------------------
template <int ACT, int OUT_DYN>
__global__ __launch_bounds__(256) void gemm_bt(const unsigned short* __restrict__ A,
                                               const unsigned short* __restrict__ B,
                                               void* __restrict__ C,
                                               const int* __restrict__ flag,
                                               int N, int K, int rowOff,
                                               int NT, int GM, int strip) {
    __shared__ unsigned short As[128 * 32];
    __shared__ unsigned short Bs[128 * 32];

    // ---- block swizzle ----
    int flat = blockIdx.x;
    int mt, nt;
    if (strip > 0) {
        int xcd = flat & 7;
        int s = flat >> 3;
        int perPanel = GM * NT;
        int p = s / perPanel;
        int r = s - p * perPanel;
        nt = r / GM;
        mt = xcd * strip + p * GM + (r - nt * GM);
    } else {
        int perPanel = GM * NT;
        int p = flat / perPanel;
        int r = flat - p * perPanel;
        nt = r / GM;
        mt = p * GM + (r - nt * GM);
    }
    const int tileM = mt * 128;
    const int tileN = nt * 128;

    const int tid = threadIdx.x;
    const int lane = tid & 63;
    const int wave = tid >> 6;
    const int fl = OUT_DYN ? flag[0] : 1;

    const int wm = wave & 1, wn = wave >> 1;
    const int m0 = wm * 64, n0 = wn * 64;

    const int srow = wave * 32 + (lane >> 2);
    const int scol = (lane & 3) * 8;

    floatx4 acc[4][4];
#pragma unroll
    for (int i = 0; i < 4; i++)
#pragma unroll
        for (int j = 0; j < 4; j++) acc[i][j] = (floatx4)0.0f;

    const int fr = lane & 15;        // fragment row within 16
    const int fk = (lane >> 4) * 8;  // fragment k offset

    const unsigned short* Abase = A + (size_t)(tileM + srow) * K + scol;
    const unsigned short* Bbase = B + (size_t)(tileN + srow) * K + scol;
    unsigned short* AsDst = As + wave * 1024;
    unsigned short* BsDst = Bs + wave * 1024;

    for (int k0 = 0; k0 < K; k0 += 32) {
        __builtin_amdgcn_global_load_lds(
            (const __attribute__((address_space(1))) unsigned int*)(Abase + k0),
            (__attribute__((address_space(3))) unsigned int*)(AsDst), 16, 0, 0);
        __builtin_amdgcn_global_load_lds(
            (const __attribute__((address_space(1))) unsigned int*)(Abase + k0 + (size_t)16 * K),
            (__attribute__((address_space(3))) unsigned int*)(AsDst + 512), 16, 0, 0);
        __builtin_amdgcn_global_load_lds(
            (const __attribute__((address_space(1))) unsigned int*)(Bbase + k0),
            (__attribute__((address_space(3))) unsigned int*)(BsDst), 16, 0, 0);
        __builtin_amdgcn_global_load_lds(
            (const __attribute__((address_space(1))) unsigned int*)(Bbase + k0 + (size_t)16 * K),
            (__attribute__((address_space(3))) unsigned int*)(BsDst + 512), 16, 0, 0);

        __syncthreads();

        short8 af[4], bfr[4];
#pragma unroll
        for (int i = 0; i < 4; i++) {
            af[i] = *(const short8*)&As[(m0 + i * 16 + fr) * 32 + fk];
            bfr[i] = *(const short8*)&Bs[(n0 + i * 16 + fr) * 32 + fk];
        }
#pragma unroll
        for (int mi = 0; mi < 4; mi++)
#pragma unroll
            for (int ni = 0; ni < 4; ni++)
                acc[mi][ni] = __builtin_amdgcn_mfma_f32_16x16x32_bf16(af[mi], bfr[ni],
                                                                      acc[mi][ni], 0, 0, 0);
        __syncthreads();
    }

    // epilogue: C/D layout col=lane&15, row=(lane>>4)*4+reg
#pragma unroll
    for (int mi = 0; mi < 4; mi++) {
        int rbase = tileM + m0 + mi * 16 + (lane >> 4) * 4;
#pragma unroll
        for (int ni = 0; ni < 4; ni++) {
            int c = tileN + n0 + ni * 16 + (lane & 15);
#pragma unroll
            for (int r = 0; r < 4; r++) {
                float v = acc[mi][ni][r];
                if (ACT) v = gelu_tanh(v);
                size_t idx = (size_t)(rowOff + rbase + r) * N + c;
                if (fl)
                    ((unsigned short*)C)[idx] = f2bf(v);
                else
                    ((float*)C)[idx] = v;
            }
        }
    }
}

// largest divisor of n that is <= cap
static inline int div_le(int n, int cap) {
    for (int g = cap; g > 1; --g)
        if (n % g == 0) return g;
    return 1;
}

// ---------------------------------------------------------------------------
extern "C" void kernel_launch(void* const* d_in, const int* in_sizes, int n_in,
                              void* d_out, int out_size, void* d_ws, size_t ws_size,
                              hipStream_t stream) {
    const int T = 16384, D_IN = 1024, D_MID = 4096, D_OUT = 1024;

    // ws layout: [flag 256B][w_up 8MiB][w_dn 8MiB][x_bf16 32MiB][a slice ...]
    char* ws = (char*)d_ws;
    int* flag = (int*)ws;
    unsigned short* w_up = (unsigned short*)(ws + 256);
    unsigned short* w_dn = w_up + (size_t)D_MID * D_IN;
    unsigned short* x_bf = w_dn + (size_t)D_OUT * D_MID;
    unsigned short* a_buf = x_bf + (size_t)T * D_IN;

    size_t used = 256 + ((size_t)D_MID * D_IN + (size_t)D_OUT * D_MID + (size_t)T * D_IN) * 2;
    size_t avail = ws_size > used ? ws_size - used : 0;
    long tc = (long)(avail / ((size_t)D_MID * 2));
    tc = (tc / 128) * 128;
    if (tc > T) tc = T;
    if (tc < 128) tc = 128;  // last resort; needs ws_size >= ~49 MiB
    const int Tc = (int)tc;

    detect_dtype<<<dim3(1), dim3(1), 0, stream>>>((const unsigned int*)d_in[5], flag);

    {
        int total8 = T * D_IN / 8;
        convert_x<<<dim3((total8 + 255) / 256), dim3(256), 0, stream>>>(d_in[0], x_bf, flag,
                                                                        total8);
    }
    {
        int waves = D_MID * (D_IN / 128);  // 32768
        fwht_weights<<<dim3(waves / 4), dim3(256), 0, stream>>>(d_in[1], d_in[2], d_in[5], w_up,
                                                                flag, D_IN, D_IN / 128, waves);
    }
    {
        int waves = D_OUT * (D_MID / 128);  // 32768
        fwht_weights<<<dim3(waves / 4), dim3(256), 0, stream>>>(d_in[3], d_in[4], d_in[6], w_dn,
                                                                flag, D_MID, D_MID / 128, waves);
    }

    for (int r0 = 0; r0 < T; r0 += Tc) {
        int Ms = (T - r0 < Tc) ? (T - r0) : Tc;
        int MT = Ms / 128;
        int strip = (MT % 8 == 0) ? MT / 8 : 0;

        // GEMM1: A-tile 256KB -> GM up to 16 keeps panel <= 4MiB (L2)
        {
            int NT = D_MID / 128;  // 32
            int GM = (strip > 0) ? div_le(strip, 16) : div_le(MT, 4);
            gemm_bt<1, 0><<<dim3(MT * NT), dim3(256), 0, stream>>>(
                x_bf + (size_t)r0 * D_IN, w_up, a_buf, flag, D_MID, D_IN, 0, NT, GM, strip);
        }
        // GEMM2: A-tile 1MiB -> GM=4 keeps panel ~4MiB (L2)
        {
            int NT = D_OUT / 128;  // 8
            int GM = (strip > 0) ? div_le(strip, 4) : div_le(MT, 4);
            gemm_bt<0, 1><<<dim3(MT * NT), dim3(256), 0, stream>>>(
                a_buf, w_dn, d_out, flag, D_OUT, D_MID, r0, NT, GM, strip);
        }
    }
}

// Round 4
// 551.280 us; speedup vs baseline: 1.0447x; 1.0062x over previous
//
#include <hip/hip_runtime.h>
#include <hip/hip_bf16.h>
#include <stdint.h>

// ---------------------------------------------------------------------------
// E8RHT MLP:  out = ( gelu( rht(x) @ Wup^T ) -> rht -> @ Wdn^T )
// Folded: W_eff[o,:] = signs * blockwise-FWHT(wq[o,:]) * scale[o] / sqrt(128),
// so the hot path is two plain B^T GEMMs with a fused gelu epilogue.
// R4: (a) XOR bank-conflict swizzle on the LDS k-group (row 64B = 16 banks ->
//     8-way conflict without it; 2-way with it, which is free);
//     (b) single merged prep kernel (convert + 2x FWHT), dtype flag derived
//     in-kernel from signs[0] (f32 -> low 16 bits of word 0 are 0).
// ---------------------------------------------------------------------------

typedef __attribute__((ext_vector_type(8))) short short8;
typedef __attribute__((ext_vector_type(4))) float floatx4;

__device__ __forceinline__ float bf2f(unsigned int u16) {
    union { unsigned int i; float f; } v;
    v.i = u16 << 16;
    return v.f;
}

__device__ __forceinline__ unsigned short f2bf(float f) {
    union { float f; unsigned int i; } v;
    v.f = f;
    unsigned int r = v.i + 0x7FFFu + ((v.i >> 16) & 1u);  // RTNE
    return (unsigned short)(r >> 16);
}

// tanh-approx gelu, matching jax.nn.gelu(approximate=True).
__device__ __forceinline__ float gelu_tanh(float x) {
    float u = 0.7978845608028654f * (x + 0.044715f * x * x * x);
    float e = __expf(2.0f * u);
    float t = 1.0f - 2.0f / (e + 1.0f);
    return 0.5f * x * (1.0f + t);
}

// dtype flag: signs[0] is exactly +-1. f32 word0 low16 == 0; bf16 != 0.
__device__ __forceinline__ int dtype_flag(const void* signs_raw) {
    return ((*(const unsigned int*)signs_raw) & 0xFFFFu) ? 1 : 0;
}

// ---------------------------------------------------------------------------
// FWHT of one 128-block of one weight row (device helper).
// Lane holds elements 2l, 2l+1; in-lane butterfly + 6 shfl_xor stages.
// ---------------------------------------------------------------------------
__device__ __forceinline__ void fwht_block(const void* wq, const void* scale,
                                           const void* signs, unsigned short* out,
                                           int fl, int D, int nblk, int gwave, int lane) {
    int o = gwave / nblk;
    int blk = gwave - o * nblk;
    size_t base = (size_t)o * D + (size_t)blk * 128;

    float v0, v1, s0, s1, sc;
    if (fl) {  // bf16 inputs
        unsigned int p = ((const unsigned int*)((const unsigned short*)wq + base))[lane];
        v0 = bf2f(p & 0xffffu);
        v1 = bf2f(p >> 16);
        unsigned int sp =
            ((const unsigned int*)((const unsigned short*)signs + (size_t)blk * 128))[lane];
        s0 = bf2f(sp & 0xffffu);
        s1 = bf2f(sp >> 16);
        sc = bf2f(((const unsigned short*)scale)[o]);
    } else {  // f32 inputs
        const float* wf = (const float*)wq + base;
        v0 = wf[2 * lane];
        v1 = wf[2 * lane + 1];
        const float* sf = (const float*)signs + (size_t)blk * 128;
        s0 = sf[2 * lane];
        s1 = sf[2 * lane + 1];
        sc = ((const float*)scale)[o];
    }

    {
        float a = v0, b = v1;
        v0 = a + b;
        v1 = a - b;
    }
#pragma unroll
    for (int m = 1; m <= 32; m <<= 1) {
        float p0 = __shfl_xor(v0, m, 64);
        float p1 = __shfl_xor(v1, m, 64);
        if (lane & m) {
            v0 = p0 - v0;
            v1 = p1 - v1;
        } else {
            v0 = v0 + p0;
            v1 = v1 + p1;
        }
    }

    sc *= 0.08838834764831845f;  // 1/sqrt(128)
    unsigned short o0 = f2bf(v0 * sc * s0);
    unsigned short o1 = f2bf(v1 * sc * s1);
    ((unsigned int*)(out + base))[lane] = (unsigned int)o0 | ((unsigned int)o1 << 16);
}

// ---------------------------------------------------------------------------
// Merged prep: [0,nbX) convert x -> bf16; [nbX,nbX+nbW) FWHT w_up;
// [nbX+nbW, nbX+2*nbW) FWHT w_dn. 256 threads/block.
// ---------------------------------------------------------------------------
__global__ __launch_bounds__(256) void prep(const void* __restrict__ x,
                                            const void* __restrict__ up_wq,
                                            const void* __restrict__ up_scale,
                                            const void* __restrict__ dn_wq,
                                            const void* __restrict__ dn_scale,
                                            const void* __restrict__ up_signs,
                                            const void* __restrict__ dn_signs,
                                            unsigned short* __restrict__ x_bf,
                                            unsigned short* __restrict__ w_up,
                                            unsigned short* __restrict__ w_dn,
                                            int nbX, int nbW, int D_IN, int D_MID) {
    const int fl = dtype_flag(up_signs);
    const int bid = blockIdx.x;
    if (bid < nbX) {
        // convert x: 8 elements per thread
        size_t e = ((size_t)bid * 256 + threadIdx.x) * 8;
        if (fl) {
            *(uint4*)(x_bf + e) = *(const uint4*)((const unsigned short*)x + e);
        } else {
            const float* xf = (const float*)x + e;
            uint4 r;
            r.x = (unsigned)f2bf(xf[0]) | ((unsigned)f2bf(xf[1]) << 16);
            r.y = (unsigned)f2bf(xf[2]) | ((unsigned)f2bf(xf[3]) << 16);
            r.z = (unsigned)f2bf(xf[4]) | ((unsigned)f2bf(xf[5]) << 16);
            r.w = (unsigned)f2bf(xf[6]) | ((unsigned)f2bf(xf[7]) << 16);
            *(uint4*)(x_bf + e) = r;
        }
    } else if (bid < nbX + nbW) {
        int gwave = (bid - nbX) * 4 + (threadIdx.x >> 6);
        fwht_block(up_wq, up_scale, up_signs, w_up, fl, D_IN, D_IN / 128, gwave,
                   threadIdx.x & 63);
    } else {
        int gwave = (bid - nbX - nbW) * 4 + (threadIdx.x >> 6);
        fwht_block(dn_wq, dn_scale, dn_signs, w_dn, fl, D_MID, D_MID / 128, gwave,
                   threadIdx.x & 63);
    }
}

// ---------------------------------------------------------------------------
// B^T GEMM: C[M,N] = A[M,K] @ B[N,K]^T, bf16 in, fp32 accum.
// 128x128 tile, BK=32, 4 waves (2x2), 4x4 of 16x16x32 MFMA/wave, m97 staging.
// LDS bank-conflict XOR swizzle: 16B k-group slot sg of LDS row r holds
// global k-group sg ^ ((r>>1)&3). Staging picks the matching global column;
// reads use sg = gk ^ ((fr>>1)&3) (constant per lane -> folds into base addr).
// XCD-aware swizzle: strip>0: XCD flat%8 owns an M-strip; GM-panel sweep.
// ---------------------------------------------------------------------------
template <int ACT, int OUT_DYN>
__global__ __launch_bounds__(256) void gemm_bt(const unsigned short* __restrict__ A,
                                               const unsigned short* __restrict__ B,
                                               void* __restrict__ C,
                                               const void* __restrict__ sflag,
                                               int N, int K, int rowOff,
                                               int NT, int GM, int strip) {
    __shared__ unsigned short As[128 * 32];
    __shared__ unsigned short Bs[128 * 32];

    // ---- block swizzle ----
    int flat = blockIdx.x;
    int mt, nt;
    if (strip > 0) {
        int xcd = flat & 7;
        int s = flat >> 3;
        int perPanel = GM * NT;
        int p = s / perPanel;
        int r = s - p * perPanel;
        nt = r / GM;
        mt = xcd * strip + p * GM + (r - nt * GM);
    } else {
        int perPanel = GM * NT;
        int p = flat / perPanel;
        int r = flat - p * perPanel;
        nt = r / GM;
        mt = p * GM + (r - nt * GM);
    }
    const int tileM = mt * 128;
    const int tileN = nt * 128;

    const int tid = threadIdx.x;
    const int lane = tid & 63;
    const int wave = tid >> 6;
    const int fl = OUT_DYN ? dtype_flag(sflag) : 1;

    const int wm = wave & 1, wn = wave >> 1;
    const int m0 = wm * 64, n0 = wn * 64;

    // staging: lane L -> LDS row srow, 16B slot (L&3); content = global
    // k-group (L&3) ^ ((srow>>1)&3). Same swizzle term for chunk 1 (row+16).
    const int srow = wave * 32 + (lane >> 2);
    const int scol = (((lane & 3) ^ ((srow >> 1) & 3)) * 8);

    floatx4 acc[4][4];
#pragma unroll
    for (int i = 0; i < 4; i++)
#pragma unroll
        for (int j = 0; j < 4; j++) acc[i][j] = (floatx4)0.0f;

    const int fr = lane & 15;  // fragment row within 16
    // swizzled k-group slot for reads: gk ^ ((row>>1)&3); row-block bases are
    // multiples of 16 so (row>>1)&3 == (fr>>1)&3 for every fragment.
    const int fks = (((lane >> 4) ^ ((fr >> 1) & 3)) * 8);

    const unsigned short* Abase = A + (size_t)(tileM + srow) * K + scol;
    const unsigned short* Bbase = B + (size_t)(tileN + srow) * K + scol;
    unsigned short* AsDst = As + wave * 1024;
    unsigned short* BsDst = Bs + wave * 1024;

    for (int k0 = 0; k0 < K; k0 += 32) {
        __builtin_amdgcn_global_load_lds(
            (const __attribute__((address_space(1))) unsigned int*)(Abase + k0),
            (__attribute__((address_space(3))) unsigned int*)(AsDst), 16, 0, 0);
        __builtin_amdgcn_global_load_lds(
            (const __attribute__((address_space(1))) unsigned int*)(Abase + k0 + (size_t)16 * K),
            (__attribute__((address_space(3))) unsigned int*)(AsDst + 512), 16, 0, 0);
        __builtin_amdgcn_global_load_lds(
            (const __attribute__((address_space(1))) unsigned int*)(Bbase + k0),
            (__attribute__((address_space(3))) unsigned int*)(BsDst), 16, 0, 0);
        __builtin_amdgcn_global_load_lds(
            (const __attribute__((address_space(1))) unsigned int*)(Bbase + k0 + (size_t)16 * K),
            (__attribute__((address_space(3))) unsigned int*)(BsDst + 512), 16, 0, 0);

        __syncthreads();

        short8 af[4], bfr[4];
#pragma unroll
        for (int i = 0; i < 4; i++) {
            af[i] = *(const short8*)&As[(m0 + i * 16 + fr) * 32 + fks];
            bfr[i] = *(const short8*)&Bs[(n0 + i * 16 + fr) * 32 + fks];
        }
#pragma unroll
        for (int mi = 0; mi < 4; mi++)
#pragma unroll
            for (int ni = 0; ni < 4; ni++)
                acc[mi][ni] = __builtin_amdgcn_mfma_f32_16x16x32_bf16(af[mi], bfr[ni],
                                                                      acc[mi][ni], 0, 0, 0);
        __syncthreads();
    }

    // epilogue: C/D layout col=lane&15, row=(lane>>4)*4+reg
#pragma unroll
    for (int mi = 0; mi < 4; mi++) {
        int rbase = tileM + m0 + mi * 16 + (lane >> 4) * 4;
#pragma unroll
        for (int ni = 0; ni < 4; ni++) {
            int c = tileN + n0 + ni * 16 + (lane & 15);
#pragma unroll
            for (int r = 0; r < 4; r++) {
                float v = acc[mi][ni][r];
                if (ACT) v = gelu_tanh(v);
                size_t idx = (size_t)(rowOff + rbase + r) * N + c;
                if (fl)
                    ((unsigned short*)C)[idx] = f2bf(v);
                else
                    ((float*)C)[idx] = v;
            }
        }
    }
}

// largest divisor of n that is <= cap
static inline int div_le(int n, int cap) {
    for (int g = cap; g > 1; --g)
        if (n % g == 0) return g;
    return 1;
}

// ---------------------------------------------------------------------------
extern "C" void kernel_launch(void* const* d_in, const int* in_sizes, int n_in,
                              void* d_out, int out_size, void* d_ws, size_t ws_size,
                              hipStream_t stream) {
    const int T = 16384, D_IN = 1024, D_MID = 4096, D_OUT = 1024;

    // ws layout: [w_up 8MiB][w_dn 8MiB][x_bf16 32MiB][a slice ...]
    unsigned short* w_up = (unsigned short*)d_ws;
    unsigned short* w_dn = w_up + (size_t)D_MID * D_IN;
    unsigned short* x_bf = w_dn + (size_t)D_OUT * D_MID;
    unsigned short* a_buf = x_bf + (size_t)T * D_IN;

    size_t used = ((size_t)D_MID * D_IN + (size_t)D_OUT * D_MID + (size_t)T * D_IN) * 2;
    size_t avail = ws_size > used ? ws_size - used : 0;
    long tc = (long)(avail / ((size_t)D_MID * 2));
    tc = (tc / 128) * 128;
    if (tc > T) tc = T;
    if (tc < 128) tc = 128;  // last resort; needs ws_size >= ~49 MiB
    const int Tc = (int)tc;

    {
        int nbX = (T * D_IN / 8) / 256;                 // 8192
        int nbW = (D_MID * (D_IN / 128)) / 4;           // 8192 (== dn wave count / 4)
        prep<<<dim3(nbX + 2 * nbW), dim3(256), 0, stream>>>(
            d_in[0], d_in[1], d_in[2], d_in[3], d_in[4], d_in[5], d_in[6], x_bf, w_up, w_dn,
            nbX, nbW, D_IN, D_MID);
    }

    for (int r0 = 0; r0 < T; r0 += Tc) {
        int Ms = (T - r0 < Tc) ? (T - r0) : Tc;
        int MT = Ms / 128;
        int strip = (MT % 8 == 0) ? MT / 8 : 0;

        // GEMM1: A-tile 256KB -> GM up to 16 keeps panel <= 4MiB (L2)
        {
            int NT = D_MID / 128;  // 32
            int GM = (strip > 0) ? div_le(strip, 16) : div_le(MT, 4);
            gemm_bt<1, 0><<<dim3(MT * NT), dim3(256), 0, stream>>>(
                x_bf + (size_t)r0 * D_IN, w_up, a_buf, d_in[5], D_MID, D_IN, 0, NT, GM, strip);
        }
        // GEMM2: A-tile 1MiB -> GM=4 keeps panel ~4MiB (L2)
        {
            int NT = D_OUT / 128;  // 8
            int GM = (strip > 0) ? div_le(strip, 4) : div_le(MT, 4);
            gemm_bt<0, 1><<<dim3(MT * NT), dim3(256), 0, stream>>>(
                a_buf, w_dn, d_out, d_in[5], D_OUT, D_MID, r0, NT, GM, strip);
        }
    }
}

// Round 5
// 503.259 us; speedup vs baseline: 1.1444x; 1.0954x over previous
//
#include <hip/hip_runtime.h>
#include <hip/hip_bf16.h>
#include <stdint.h>

// ---------------------------------------------------------------------------
// E8RHT MLP:  out = ( gelu( rht(x) @ Wup^T ) -> rht -> @ Wdn^T )
// Folded: W_eff[o,:] = signs * blockwise-FWHT(wq[o,:]) * scale[o] / sqrt(128),
// so the hot path is two plain B^T GEMMs with a fused gelu epilogue.
// R5: (a) __launch_bounds__(256,4): force <=128 unified regs -> 4 blocks/CU
//     (R4 showed 140 regs -> 2.5 blocks/CU, latency-bound at MfmaUtil 25%);
//     (b) switch compute core to v_mfma_f32_32x32x16_bf16, 2x2 tiles/wave
//     (m119: +20% pipe ceiling, half the issue slots, same LDS traffic,
//      same 64 AGPR; epilogue stores become 64B runs instead of 32B).
// ---------------------------------------------------------------------------

typedef __attribute__((ext_vector_type(8))) short short8;
typedef __attribute__((ext_vector_type(16))) float floatx16;

__device__ __forceinline__ float bf2f(unsigned int u16) {
    union { unsigned int i; float f; } v;
    v.i = u16 << 16;
    return v.f;
}

__device__ __forceinline__ unsigned short f2bf(float f) {
    union { float f; unsigned int i; } v;
    v.f = f;
    unsigned int r = v.i + 0x7FFFu + ((v.i >> 16) & 1u);  // RTNE
    return (unsigned short)(r >> 16);
}

// tanh-approx gelu, matching jax.nn.gelu(approximate=True).
__device__ __forceinline__ float gelu_tanh(float x) {
    float u = 0.7978845608028654f * (x + 0.044715f * x * x * x);
    float e = __expf(2.0f * u);
    float t = 1.0f - 2.0f / (e + 1.0f);
    return 0.5f * x * (1.0f + t);
}

// dtype flag: signs[0] is exactly +-1. f32 word0 low16 == 0; bf16 != 0.
__device__ __forceinline__ int dtype_flag(const void* signs_raw) {
    return ((*(const unsigned int*)signs_raw) & 0xFFFFu) ? 1 : 0;
}

// ---------------------------------------------------------------------------
// FWHT of one 128-block of one weight row (device helper).
// ---------------------------------------------------------------------------
__device__ __forceinline__ void fwht_block(const void* wq, const void* scale,
                                           const void* signs, unsigned short* out,
                                           int fl, int D, int nblk, int gwave, int lane) {
    int o = gwave / nblk;
    int blk = gwave - o * nblk;
    size_t base = (size_t)o * D + (size_t)blk * 128;

    float v0, v1, s0, s1, sc;
    if (fl) {  // bf16 inputs
        unsigned int p = ((const unsigned int*)((const unsigned short*)wq + base))[lane];
        v0 = bf2f(p & 0xffffu);
        v1 = bf2f(p >> 16);
        unsigned int sp =
            ((const unsigned int*)((const unsigned short*)signs + (size_t)blk * 128))[lane];
        s0 = bf2f(sp & 0xffffu);
        s1 = bf2f(sp >> 16);
        sc = bf2f(((const unsigned short*)scale)[o]);
    } else {  // f32 inputs
        const float* wf = (const float*)wq + base;
        v0 = wf[2 * lane];
        v1 = wf[2 * lane + 1];
        const float* sf = (const float*)signs + (size_t)blk * 128;
        s0 = sf[2 * lane];
        s1 = sf[2 * lane + 1];
        sc = ((const float*)scale)[o];
    }

    {
        float a = v0, b = v1;
        v0 = a + b;
        v1 = a - b;
    }
#pragma unroll
    for (int m = 1; m <= 32; m <<= 1) {
        float p0 = __shfl_xor(v0, m, 64);
        float p1 = __shfl_xor(v1, m, 64);
        if (lane & m) {
            v0 = p0 - v0;
            v1 = p1 - v1;
        } else {
            v0 = v0 + p0;
            v1 = v1 + p1;
        }
    }

    sc *= 0.08838834764831845f;  // 1/sqrt(128)
    unsigned short o0 = f2bf(v0 * sc * s0);
    unsigned short o1 = f2bf(v1 * sc * s1);
    ((unsigned int*)(out + base))[lane] = (unsigned int)o0 | ((unsigned int)o1 << 16);
}

// ---------------------------------------------------------------------------
// Merged prep: [0,nbX) convert x -> bf16; [nbX,nbX+nbW) FWHT w_up;
// [nbX+nbW, nbX+2*nbW) FWHT w_dn. 256 threads/block.
// ---------------------------------------------------------------------------
__global__ __launch_bounds__(256) void prep(const void* __restrict__ x,
                                            const void* __restrict__ up_wq,
                                            const void* __restrict__ up_scale,
                                            const void* __restrict__ dn_wq,
                                            const void* __restrict__ dn_scale,
                                            const void* __restrict__ up_signs,
                                            const void* __restrict__ dn_signs,
                                            unsigned short* __restrict__ x_bf,
                                            unsigned short* __restrict__ w_up,
                                            unsigned short* __restrict__ w_dn,
                                            int nbX, int nbW, int D_IN, int D_MID) {
    const int fl = dtype_flag(up_signs);
    const int bid = blockIdx.x;
    if (bid < nbX) {
        size_t e = ((size_t)bid * 256 + threadIdx.x) * 8;
        if (fl) {
            *(uint4*)(x_bf + e) = *(const uint4*)((const unsigned short*)x + e);
        } else {
            const float* xf = (const float*)x + e;
            uint4 r;
            r.x = (unsigned)f2bf(xf[0]) | ((unsigned)f2bf(xf[1]) << 16);
            r.y = (unsigned)f2bf(xf[2]) | ((unsigned)f2bf(xf[3]) << 16);
            r.z = (unsigned)f2bf(xf[4]) | ((unsigned)f2bf(xf[5]) << 16);
            r.w = (unsigned)f2bf(xf[6]) | ((unsigned)f2bf(xf[7]) << 16);
            *(uint4*)(x_bf + e) = r;
        }
    } else if (bid < nbX + nbW) {
        int gwave = (bid - nbX) * 4 + (threadIdx.x >> 6);
        fwht_block(up_wq, up_scale, up_signs, w_up, fl, D_IN, D_IN / 128, gwave,
                   threadIdx.x & 63);
    } else {
        int gwave = (bid - nbX - nbW) * 4 + (threadIdx.x >> 6);
        fwht_block(dn_wq, dn_scale, dn_signs, w_dn, fl, D_MID, D_MID / 128, gwave,
                   threadIdx.x & 63);
    }
}

// ---------------------------------------------------------------------------
// B^T GEMM: C[M,N] = A[M,K] @ B[N,K]^T, bf16 in, fp32 accum.
// 128x128 tile, BK=32, 4 waves (2x2), 2x2 of 32x32x16 MFMA per wave.
// LDS XOR swizzle: slot s of row r holds global k-group s ^ ((r>>1)&3);
// read slot = kgroup ^ ((r>>1)&3) -- lane-constant (folds into base).
// 32x32x16 layouts: A[m=lane&31][k=(lane>>5)*8+j];
// C/D col=lane&31, row=(reg&3)+8*(reg>>2)+4*(lane>>5)  [m74/m101].
// XCD swizzle: strip>0: XCD flat%8 owns an M-strip; GM-panel sweep n-outer.
// ---------------------------------------------------------------------------
template <int ACT, int OUT_DYN>
__global__ __launch_bounds__(256, 4) void gemm_bt(const unsigned short* __restrict__ A,
                                                  const unsigned short* __restrict__ B,
                                                  void* __restrict__ C,
                                                  const void* __restrict__ sflag,
                                                  int N, int K, int rowOff,
                                                  int NT, int GM, int strip) {
    __shared__ unsigned short As[128 * 32];
    __shared__ unsigned short Bs[128 * 32];

    // ---- block swizzle ----
    int flat = blockIdx.x;
    int mt, nt;
    if (strip > 0) {
        int xcd = flat & 7;
        int s = flat >> 3;
        int perPanel = GM * NT;
        int p = s / perPanel;
        int r = s - p * perPanel;
        nt = r / GM;
        mt = xcd * strip + p * GM + (r - nt * GM);
    } else {
        int perPanel = GM * NT;
        int p = flat / perPanel;
        int r = flat - p * perPanel;
        nt = r / GM;
        mt = p * GM + (r - nt * GM);
    }
    const int tileM = mt * 128;
    const int tileN = nt * 128;

    const int tid = threadIdx.x;
    const int lane = tid & 63;
    const int wave = tid >> 6;
    const int fl = OUT_DYN ? dtype_flag(sflag) : 1;

    const int wm = wave & 1, wn = wave >> 1;
    const int m0 = wm * 64, n0 = wn * 64;

    // staging: lane L -> LDS row srow, 16B slot (L&3); content = global
    // k-group (L&3) ^ ((srow>>1)&3). Same term for chunk 1 (row+16).
    const int srow = wave * 32 + (lane >> 2);
    const int scol = (((lane & 3) ^ ((srow >> 1) & 3)) * 8);

    floatx16 acc[2][2];
#pragma unroll
    for (int i = 0; i < 2; i++)
#pragma unroll
        for (int j = 0; j < 2; j++) acc[i][j] = (floatx16)0.0f;

    // fragment addressing (32x32x16): row = base + (lane&31), kgroup(ks) =
    // ks*2 + (lane>>5); slot = kgroup ^ ((row>>1)&3) -> slot(ks=1)=slot(0)^2.
    const int r31 = lane & 31;
    const int kg = lane >> 5;
    const int sl0 = kg ^ ((r31 >> 1) & 3);  // (row>>1)&3 invariant to +32/+64
    const int sl1 = sl0 ^ 2;

    // element offsets in As/Bs (row stride 32 elems)
    const int eA[2][2] = {
        {(m0 + r31) * 32 + sl0 * 8, (m0 + r31) * 32 + sl1 * 8},
        {(m0 + 32 + r31) * 32 + sl0 * 8, (m0 + 32 + r31) * 32 + sl1 * 8}};
    const int eB[2][2] = {
        {(n0 + r31) * 32 + sl0 * 8, (n0 + r31) * 32 + sl1 * 8},
        {(n0 + 32 + r31) * 32 + sl0 * 8, (n0 + 32 + r31) * 32 + sl1 * 8}};

    const unsigned short* Abase = A + (size_t)(tileM + srow) * K + scol;
    const unsigned short* Bbase = B + (size_t)(tileN + srow) * K + scol;
    unsigned short* AsDst = As + wave * 1024;
    unsigned short* BsDst = Bs + wave * 1024;

    for (int k0 = 0; k0 < K; k0 += 32) {
        __builtin_amdgcn_global_load_lds(
            (const __attribute__((address_space(1))) unsigned int*)(Abase + k0),
            (__attribute__((address_space(3))) unsigned int*)(AsDst), 16, 0, 0);
        __builtin_amdgcn_global_load_lds(
            (const __attribute__((address_space(1))) unsigned int*)(Abase + k0 + (size_t)16 * K),
            (__attribute__((address_space(3))) unsigned int*)(AsDst + 512), 16, 0, 0);
        __builtin_amdgcn_global_load_lds(
            (const __attribute__((address_space(1))) unsigned int*)(Bbase + k0),
            (__attribute__((address_space(3))) unsigned int*)(BsDst), 16, 0, 0);
        __builtin_amdgcn_global_load_lds(
            (const __attribute__((address_space(1))) unsigned int*)(Bbase + k0 + (size_t)16 * K),
            (__attribute__((address_space(3))) unsigned int*)(BsDst + 512), 16, 0, 0);

        __syncthreads();

        short8 af[2][2], bf[2][2];
#pragma unroll
        for (int mi = 0; mi < 2; mi++)
#pragma unroll
            for (int ks = 0; ks < 2; ks++) {
                af[mi][ks] = *(const short8*)&As[eA[mi][ks]];
                bf[mi][ks] = *(const short8*)&Bs[eB[mi][ks]];
            }
#pragma unroll
        for (int mi = 0; mi < 2; mi++)
#pragma unroll
            for (int ni = 0; ni < 2; ni++)
#pragma unroll
                for (int ks = 0; ks < 2; ks++)
                    acc[mi][ni] = __builtin_amdgcn_mfma_f32_32x32x16_bf16(
                        af[mi][ks], bf[ni][ks], acc[mi][ni], 0, 0, 0);
        __syncthreads();
    }

    // epilogue: C/D col=lane&31, row=(reg&3)+8*(reg>>2)+4*(lane>>5)
#pragma unroll
    for (int mi = 0; mi < 2; mi++) {
        int rb0 = tileM + m0 + mi * 32 + kg * 4;
#pragma unroll
        for (int ni = 0; ni < 2; ni++) {
            int c = tileN + n0 + ni * 32 + r31;
#pragma unroll
            for (int g = 0; g < 4; g++) {
#pragma unroll
                for (int r = 0; r < 4; r++) {
                    float v = acc[mi][ni][g * 4 + r];
                    if (ACT) v = gelu_tanh(v);
                    size_t idx = (size_t)(rowOff + rb0 + g * 8 + r) * N + c;
                    if (fl)
                        ((unsigned short*)C)[idx] = f2bf(v);
                    else
                        ((float*)C)[idx] = v;
                }
            }
        }
    }
}

// largest divisor of n that is <= cap
static inline int div_le(int n, int cap) {
    for (int g = cap; g > 1; --g)
        if (n % g == 0) return g;
    return 1;
}

// ---------------------------------------------------------------------------
extern "C" void kernel_launch(void* const* d_in, const int* in_sizes, int n_in,
                              void* d_out, int out_size, void* d_ws, size_t ws_size,
                              hipStream_t stream) {
    const int T = 16384, D_IN = 1024, D_MID = 4096, D_OUT = 1024;

    // ws layout: [w_up 8MiB][w_dn 8MiB][x_bf16 32MiB][a slice ...]
    unsigned short* w_up = (unsigned short*)d_ws;
    unsigned short* w_dn = w_up + (size_t)D_MID * D_IN;
    unsigned short* x_bf = w_dn + (size_t)D_OUT * D_MID;
    unsigned short* a_buf = x_bf + (size_t)T * D_IN;

    size_t used = ((size_t)D_MID * D_IN + (size_t)D_OUT * D_MID + (size_t)T * D_IN) * 2;
    size_t avail = ws_size > used ? ws_size - used : 0;
    long tc = (long)(avail / ((size_t)D_MID * 2));
    tc = (tc / 128) * 128;
    if (tc > T) tc = T;
    if (tc < 128) tc = 128;  // last resort; needs ws_size >= ~49 MiB
    const int Tc = (int)tc;

    {
        int nbX = (T * D_IN / 8) / 256;        // 8192
        int nbW = (D_MID * (D_IN / 128)) / 4;  // 8192 (== dn wave count / 4)
        prep<<<dim3(nbX + 2 * nbW), dim3(256), 0, stream>>>(
            d_in[0], d_in[1], d_in[2], d_in[3], d_in[4], d_in[5], d_in[6], x_bf, w_up, w_dn,
            nbX, nbW, D_IN, D_MID);
    }

    for (int r0 = 0; r0 < T; r0 += Tc) {
        int Ms = (T - r0 < Tc) ? (T - r0) : Tc;
        int MT = Ms / 128;
        int strip = (MT % 8 == 0) ? MT / 8 : 0;

        // GEMM1: A-tile 256KB -> GM up to 16 keeps panel <= 4MiB (L2)
        {
            int NT = D_MID / 128;  // 32
            int GM = (strip > 0) ? div_le(strip, 16) : div_le(MT, 4);
            gemm_bt<1, 0><<<dim3(MT * NT), dim3(256), 0, stream>>>(
                x_bf + (size_t)r0 * D_IN, w_up, a_buf, d_in[5], D_MID, D_IN, 0, NT, GM, strip);
        }
        // GEMM2: A-tile 1MiB -> GM=4 keeps panel ~4MiB (L2)
        {
            int NT = D_OUT / 128;  // 8
            int GM = (strip > 0) ? div_le(strip, 4) : div_le(MT, 4);
            gemm_bt<0, 1><<<dim3(MT * NT), dim3(256), 0, stream>>>(
                a_buf, w_dn, d_out, d_in[5], D_OUT, D_MID, r0, NT, GM, strip);
        }
    }
}